// Round 3
// baseline (484.919 us; speedup 1.0000x reference)
//
#include <hip/hip_runtime.h>

// out[s][o] = sum_i x[s][i] * dq(w[o][i]); int4 group quant, group=256, scale=max(absmax/7,1e-9)
// x: [16,4096] f32, w: [14336,4096] f32 (235 MB streamed once), out: [16,14336] f32
//
// R7 = R6 with the HBM duty-cycle fixes (resubmitted x2 — R1/R2 benches hit
// GPUAcquisitionTimeout before running; no counters were ever produced):
//  - RPW 4->2: acc[2][16]=32 VGPRs (was 64). Total demand ~90 regs, safely
//    under the 128-reg occupancy step -> 2 blocks/CU (14 waves) GUARANTEED,
//    instead of knife-edge at 128 with plain bounds.
//  - depth-2 rotating w prefetch (wn1/wn2), consume-at-TOP of the iteration:
//    the load for group G is issued in iteration G-2, so the vmcnt wait has
//    ~2 full iterations of compute cover (~1700 cyc > ~900 cyc HBM latency).
//    R6 issued at top and waited at the BOTTOM of the same iteration (<1 iter
//    of cover) -> every wave stalled on its own prefetch every group.
//  - grid 1024 x 14 rows: exactly 2 even residency rounds of 512 blocks.
// Pipe budget per group-iter per CU at RPW=2 (14 waves): HBM 28 KB ~2.7k cyc,
// LDS 224 b128-reads ~1.8k cyc, VALU ~1.6k cyc -> HBM-bound with margin.

constexpr int O_DIM  = 14336;
constexpr int I_DIM  = 4096;
constexpr int S_DIM  = 16;
constexpr int GS     = 256;           // quant group size
constexpr int NG     = I_DIM / GS;    // 16 groups
constexpr int RPW    = 2;             // rows per wave (was 4)
constexpr int NWAVE  = 7;             // waves per block
constexpr int NTHR   = 64 * NWAVE;    // 448
constexpr int RPB    = RPW * NWAVE;   // 14 rows/block -> 1024 blocks = 2 even rounds
constexpr int PH_I   = 1024;          // i-extent per x staging phase (64 KB LDS)
constexpr int NPH    = I_DIM / PH_I;  // 4 phases
constexpr int GPP    = PH_I / GS;     // 4 groups per phase

// wave64 max-reduce on the VALU pipe (validated correct in R5/R6 runs):
// 4x row_shr + row_bcast15 + row_bcast31, readlane(63) -> wave-uniform SGPR.
// Inputs >= 0, so bound_ctrl=true zero-fill is identity for max.
__device__ __forceinline__ float wave_max_dpp(float x) {
    int v = __float_as_int(x);
    int t;
    t = __builtin_amdgcn_update_dpp(0, v, 0x111, 0xf, 0xf, true); // row_shr:1
    v = __float_as_int(fmaxf(__int_as_float(v), __int_as_float(t)));
    t = __builtin_amdgcn_update_dpp(0, v, 0x112, 0xf, 0xf, true); // row_shr:2
    v = __float_as_int(fmaxf(__int_as_float(v), __int_as_float(t)));
    t = __builtin_amdgcn_update_dpp(0, v, 0x114, 0xf, 0xf, true); // row_shr:4
    v = __float_as_int(fmaxf(__int_as_float(v), __int_as_float(t)));
    t = __builtin_amdgcn_update_dpp(0, v, 0x118, 0xf, 0xf, true); // row_shr:8
    v = __float_as_int(fmaxf(__int_as_float(v), __int_as_float(t)));
    t = __builtin_amdgcn_update_dpp(0, v, 0x142, 0xf, 0xf, true); // row_bcast:15
    v = __float_as_int(fmaxf(__int_as_float(v), __int_as_float(t)));
    t = __builtin_amdgcn_update_dpp(0, v, 0x143, 0xf, 0xf, true); // row_bcast:31
    v = __float_as_int(fmaxf(__int_as_float(v), __int_as_float(t)));
    return __int_as_float(__builtin_amdgcn_readlane(v, 63));
}

__global__ __launch_bounds__(NTHR)
void qlin_kernel(const float* __restrict__ x,
                 const float* __restrict__ w,
                 float* __restrict__ out)
{
    __shared__ float xs[S_DIM][PH_I];   // 64 KB -> LDS allows 2 blocks/CU

    const int tid  = threadIdx.x;
    const int lane = tid & 63;
    const int wv   = tid >> 6;          // 0..6
    const int row0 = blockIdx.x * RPB + wv * RPW;

    const float* wp = w + (size_t)row0 * I_DIM + lane * 4;

    float acc[RPW][S_DIM];
#pragma unroll
    for (int r = 0; r < RPW; ++r)
#pragma unroll
        for (int s = 0; s < S_DIM; ++s) acc[r][s] = 0.0f;

    // depth-2 prefetch pipeline: wn1 holds group G, wn2 holds group G+1.
    float4 wcur[RPW], wn1[RPW], wn2[RPW];
#pragma unroll
    for (int r = 0; r < RPW; ++r)
        wn1[r] = *reinterpret_cast<const float4*>(wp + (size_t)r * I_DIM);
#pragma unroll
    for (int r = 0; r < RPW; ++r)
        wn2[r] = *reinterpret_cast<const float4*>(wp + (size_t)r * I_DIM + GS);

    for (int p = 0; p < NPH; ++p) {
        // ---- stage x[:, p*1024 .. +1024) into LDS (4096 float4 / 448 thr) ----
        // reg-roundtrip staging (proven correct; avoids global_load_lds
        // masked-lane edge semantics on the 4096%448 != 0 tail).
        if (p) __syncthreads();         // all waves done reading phase p-1
        for (int j = tid; j < S_DIM * (PH_I / 4); j += NTHR) {
            const int s  = j >> 8;          // float4-slot / 256-per-row
            const int i4 = (j & 255) * 4;
            *reinterpret_cast<float4*>(&xs[s][i4]) =
                *reinterpret_cast<const float4*>(
                    &x[(size_t)s * I_DIM + p * PH_I + i4]);
        }
        __syncthreads();

#pragma unroll
        for (int g = 0; g < GPP; ++g) {
            const int G = p * GPP + g;      // global group index

            // rotate the pipeline: consume oldest at the TOP of the iteration.
            // wn1's loads were issued 2 iterations ago -> vmcnt wait is ~free.
#pragma unroll
            for (int r = 0; r < RPW; ++r) { wcur[r] = wn1[r]; wn1[r] = wn2[r]; }

            // issue loads for G+2 — they have this iteration AND the next
            // (plus any barrier overlap) before their wait.
            if (G + 2 < NG) {
#pragma unroll
                for (int r = 0; r < RPW; ++r)
                    wn2[r] = *reinterpret_cast<const float4*>(
                        wp + (size_t)r * I_DIM + (G + 2) * GS);
            }

            // dequant wcur in place; absmax on VALU pipe via DPP
#pragma unroll
            for (int r = 0; r < RPW; ++r) {
                float4 v = wcur[r];
                float m = fmaxf(fmaxf(fabsf(v.x), fabsf(v.y)),
                                fmaxf(fabsf(v.z), fabsf(v.w)));
                m = wave_max_dpp(m);
                float scale = fmaxf(m * (1.0f / 7.0f), 1e-9f);
                float invs  = 1.0f / scale;
                // clamp provably dead: scale >= absmax/7 => |v*invs| <= 7
                wcur[r].x = rintf(v.x * invs) * scale;
                wcur[r].y = rintf(v.y * invs) * scale;
                wcur[r].z = rintf(v.z * invs) * scale;
                wcur[r].w = rintf(v.w * invs) * scale;
            }

            // FMA: x from LDS (lgkmcnt only — never waits on the w prefetch)
            const int xb = g * GS + lane * 4;
#pragma unroll
            for (int s = 0; s < S_DIM; ++s) {
                float4 xv = *reinterpret_cast<const float4*>(&xs[s][xb]);
#pragma unroll
                for (int r = 0; r < RPW; ++r) {
                    acc[r][s] = fmaf(wcur[r].x, xv.x, acc[r][s]);
                    acc[r][s] = fmaf(wcur[r].y, xv.y, acc[r][s]);
                    acc[r][s] = fmaf(wcur[r].z, xv.z, acc[r][s]);
                    acc[r][s] = fmaf(wcur[r].w, xv.w, acc[r][s]);
                }
            }
        }
    }

    // ---- epilogue: reduce 32 accs across 64 lanes ----
    // step 1: fold the two 32-lane halves (lanes l and l^32 hold the same
    //         index set) — 32 plain xor-adds.
    // step 2: value-splitting butterfly over 32 slots; lane l (l<32) ends
    //         with the sum of a[l], l = (r<<4)|s.
    float a[RPW * S_DIM];
#pragma unroll
    for (int r = 0; r < RPW; ++r)
#pragma unroll
        for (int s = 0; s < S_DIM; ++s) a[(r << 4) | s] = acc[r][s];

#pragma unroll
    for (int j = 0; j < RPW * S_DIM; ++j)
        a[j] += __shfl_xor(a[j], 32, 64);

#pragma unroll
    for (int m = 16; m >= 1; m >>= 1) {
        const bool hi = (lane & m) != 0;
#pragma unroll
        for (int j = 0; j < m; ++j) {
            float snd  = hi ? a[j] : a[j + m];
            float rcv  = __shfl_xor(snd, m, 64);
            float kept = hi ? a[j + m] : a[j];
            a[j] = kept + rcv;
        }
    }
    if (lane < 32) {
        const int r = (lane >> 4) & 1, s = lane & 15;
        out[s * O_DIM + (row0 + r)] = a[0];
    }
}

extern "C" void kernel_launch(void* const* d_in, const int* in_sizes, int n_in,
                              void* d_out, int out_size, void* d_ws, size_t ws_size,
                              hipStream_t stream) {
    const float* x = (const float*)d_in[0];   // 1*16*4096
    const float* w = (const float*)d_in[1];   // 14336*4096
    float* out = (float*)d_out;               // 16*14336
    dim3 grid(O_DIM / RPB);                   // 1024 blocks -> 2 even rounds of 512
    dim3 block(NTHR);                         // 448 = 7 waves
    qlin_kernel<<<grid, block, 0, stream>>>(x, w, out);
}

// Round 5
// 381.287 us; speedup vs baseline: 1.2718x; 1.2718x over previous
//
#include <hip/hip_runtime.h>

// out[s][o] = sum_i x[s][i] * dq(w[o][i]); int4 group quant, group=256, scale=max(absmax/7,1e-9)
// x: [16,4096] f32, w: [14336,4096] f32 (235 MB streamed once), out: [16,14336] f32
//
// R8 = R7 with the spill fixed (resubmitted — R4 bench hit GPUAcquisitionTimeout).
// R7 post-mortem (first real counters): VGPR_Count=128 (cap), WRITE_SIZE=263 MB
// vs 0.9 MB output -> ~262 MB scratch stores/dispatch; kernel 267 us at 1.5 TB/s
// of mostly-scratch traffic. Cause: '#pragma unroll' on the g-loop (GPP=4) let
// the scheduler hoist 4 iterations of wn2 global loads + 64 ds_read_b128 xv
// loads -> live ranges blew past the 128-reg cap. R6 (no pragma, bigger acc)
// never spilled.
// Fix: '#pragma unroll 1' pins the g-loop. Per-iteration demand: acc 32 +
// 3x8 w-bufs + xv/addr ~= 90 regs, safely under 128. Rotation costs ~24
// v_movs/iter (~5% of the 128 FMAs).
// Kept from R7 (verified PASSED in R3's run):
//  - RPW=2: acc[2][16]=32 VGPRs; 2 blocks/CU (14 waves) with margin.
//  - depth-2 rotating w prefetch (wn1/wn2), consume-at-TOP: the load for
//    group G is issued in iteration G-2 (~2 iters of cover > ~900 cyc HBM
//    latency) -> no per-iteration self-stall at the loop bottom.
//  - grid 1024 x 14 rows: two even residency rounds of 512 blocks.

constexpr int O_DIM  = 14336;
constexpr int I_DIM  = 4096;
constexpr int S_DIM  = 16;
constexpr int GS     = 256;           // quant group size
constexpr int NG     = I_DIM / GS;    // 16 groups
constexpr int RPW    = 2;             // rows per wave
constexpr int NWAVE  = 7;             // waves per block
constexpr int NTHR   = 64 * NWAVE;    // 448
constexpr int RPB    = RPW * NWAVE;   // 14 rows/block -> 1024 blocks
constexpr int PH_I   = 1024;          // i-extent per x staging phase (64 KB LDS)
constexpr int NPH    = I_DIM / PH_I;  // 4 phases
constexpr int GPP    = PH_I / GS;     // 4 groups per phase

// wave64 max-reduce on the VALU pipe (validated correct in R5/R6/R7 runs):
// 4x row_shr + row_bcast15 + row_bcast31, readlane(63) -> wave-uniform SGPR.
// Inputs >= 0, so bound_ctrl=true zero-fill is identity for max.
__device__ __forceinline__ float wave_max_dpp(float x) {
    int v = __float_as_int(x);
    int t;
    t = __builtin_amdgcn_update_dpp(0, v, 0x111, 0xf, 0xf, true); // row_shr:1
    v = __float_as_int(fmaxf(__int_as_float(v), __int_as_float(t)));
    t = __builtin_amdgcn_update_dpp(0, v, 0x112, 0xf, 0xf, true); // row_shr:2
    v = __float_as_int(fmaxf(__int_as_float(v), __int_as_float(t)));
    t = __builtin_amdgcn_update_dpp(0, v, 0x114, 0xf, 0xf, true); // row_shr:4
    v = __float_as_int(fmaxf(__int_as_float(v), __int_as_float(t)));
    t = __builtin_amdgcn_update_dpp(0, v, 0x118, 0xf, 0xf, true); // row_shr:8
    v = __float_as_int(fmaxf(__int_as_float(v), __int_as_float(t)));
    t = __builtin_amdgcn_update_dpp(0, v, 0x142, 0xf, 0xf, true); // row_bcast:15
    v = __float_as_int(fmaxf(__int_as_float(v), __int_as_float(t)));
    t = __builtin_amdgcn_update_dpp(0, v, 0x143, 0xf, 0xf, true); // row_bcast:31
    v = __float_as_int(fmaxf(__int_as_float(v), __int_as_float(t)));
    return __int_as_float(__builtin_amdgcn_readlane(v, 63));
}

__global__ __launch_bounds__(NTHR)
void qlin_kernel(const float* __restrict__ x,
                 const float* __restrict__ w,
                 float* __restrict__ out)
{
    __shared__ float xs[S_DIM][PH_I];   // 64 KB -> LDS allows 2 blocks/CU

    const int tid  = threadIdx.x;
    const int lane = tid & 63;
    const int wv   = tid >> 6;          // 0..6
    const int row0 = blockIdx.x * RPB + wv * RPW;

    const float* wp = w + (size_t)row0 * I_DIM + lane * 4;

    float acc[RPW][S_DIM];
#pragma unroll
    for (int r = 0; r < RPW; ++r)
#pragma unroll
        for (int s = 0; s < S_DIM; ++s) acc[r][s] = 0.0f;

    // depth-2 prefetch pipeline: wn1 holds group G, wn2 holds group G+1.
    float4 wcur[RPW], wn1[RPW], wn2[RPW];
#pragma unroll
    for (int r = 0; r < RPW; ++r)
        wn1[r] = *reinterpret_cast<const float4*>(wp + (size_t)r * I_DIM);
#pragma unroll
    for (int r = 0; r < RPW; ++r)
        wn2[r] = *reinterpret_cast<const float4*>(wp + (size_t)r * I_DIM + GS);

    for (int p = 0; p < NPH; ++p) {
        // ---- stage x[:, p*1024 .. +1024) into LDS (4096 float4 / 448 thr) ----
        // reg-roundtrip staging (proven correct; avoids global_load_lds
        // masked-lane edge semantics on the 4096%448 != 0 tail).
        if (p) __syncthreads();         // all waves done reading phase p-1
        for (int j = tid; j < S_DIM * (PH_I / 4); j += NTHR) {
            const int s  = j >> 8;          // float4-slot / 256-per-row
            const int i4 = (j & 255) * 4;
            *reinterpret_cast<float4*>(&xs[s][i4]) =
                *reinterpret_cast<const float4*>(
                    &x[(size_t)s * I_DIM + p * PH_I + i4]);
        }
        __syncthreads();

        // unroll 1: R7's full unroll here hoisted 4 iterations of loads and
        // blew past the 128-VGPR cap -> 263 MB of scratch spill. Do not unroll.
#pragma unroll 1
        for (int g = 0; g < GPP; ++g) {
            const int G = p * GPP + g;      // global group index

            // rotate the pipeline: consume oldest at the TOP of the iteration.
            // wn1's loads were issued 2 iterations ago -> vmcnt wait is ~free.
#pragma unroll
            for (int r = 0; r < RPW; ++r) { wcur[r] = wn1[r]; wn1[r] = wn2[r]; }

            // issue loads for G+2 — they have this iteration AND the next
            // (plus any barrier overlap) before their wait.
            if (G + 2 < NG) {
#pragma unroll
                for (int r = 0; r < RPW; ++r)
                    wn2[r] = *reinterpret_cast<const float4*>(
                        wp + (size_t)r * I_DIM + (G + 2) * GS);
            }

            // dequant wcur in place; absmax on VALU pipe via DPP
#pragma unroll
            for (int r = 0; r < RPW; ++r) {
                float4 v = wcur[r];
                float m = fmaxf(fmaxf(fabsf(v.x), fabsf(v.y)),
                                fmaxf(fabsf(v.z), fabsf(v.w)));
                m = wave_max_dpp(m);
                float scale = fmaxf(m * (1.0f / 7.0f), 1e-9f);
                float invs  = 1.0f / scale;
                // clamp provably dead: scale >= absmax/7 => |v*invs| <= 7
                wcur[r].x = rintf(v.x * invs) * scale;
                wcur[r].y = rintf(v.y * invs) * scale;
                wcur[r].z = rintf(v.z * invs) * scale;
                wcur[r].w = rintf(v.w * invs) * scale;
            }

            // FMA: x from LDS (lgkmcnt only — never waits on the w prefetch)
            const int xb = g * GS + lane * 4;
#pragma unroll
            for (int s = 0; s < S_DIM; ++s) {
                float4 xv = *reinterpret_cast<const float4*>(&xs[s][xb]);
#pragma unroll
                for (int r = 0; r < RPW; ++r) {
                    acc[r][s] = fmaf(wcur[r].x, xv.x, acc[r][s]);
                    acc[r][s] = fmaf(wcur[r].y, xv.y, acc[r][s]);
                    acc[r][s] = fmaf(wcur[r].z, xv.z, acc[r][s]);
                    acc[r][s] = fmaf(wcur[r].w, xv.w, acc[r][s]);
                }
            }
        }
    }

    // ---- epilogue: reduce 32 accs across 64 lanes ----
    // step 1: fold the two 32-lane halves (lanes l and l^32 hold the same
    //         index set) — 32 plain xor-adds.
    // step 2: value-splitting butterfly over 32 slots; lane l (l<32) ends
    //         with the sum of a[l], l = (r<<4)|s.
    float a[RPW * S_DIM];
#pragma unroll
    for (int r = 0; r < RPW; ++r)
#pragma unroll
        for (int s = 0; s < S_DIM; ++s) a[(r << 4) | s] = acc[r][s];

#pragma unroll
    for (int j = 0; j < RPW * S_DIM; ++j)
        a[j] += __shfl_xor(a[j], 32, 64);

#pragma unroll
    for (int m = 16; m >= 1; m >>= 1) {
        const bool hi = (lane & m) != 0;
#pragma unroll
        for (int j = 0; j < m; ++j) {
            float snd  = hi ? a[j] : a[j + m];
            float rcv  = __shfl_xor(snd, m, 64);
            float kept = hi ? a[j + m] : a[j];
            a[j] = kept + rcv;
        }
    }
    if (lane < 32) {
        const int r = (lane >> 4) & 1, s = lane & 15;
        out[s * O_DIM + (row0 + r)] = a[0];
    }
}

extern "C" void kernel_launch(void* const* d_in, const int* in_sizes, int n_in,
                              void* d_out, int out_size, void* d_ws, size_t ws_size,
                              hipStream_t stream) {
    const float* x = (const float*)d_in[0];   // 1*16*4096
    const float* w = (const float*)d_in[1];   // 14336*4096
    float* out = (float*)d_out;               // 16*14336
    dim3 grid(O_DIM / RPB);                   // 1024 blocks -> 2 even rounds of 512
    dim3 block(NTHR);                         // 448 = 7 waves
    qlin_kernel<<<grid, block, 0, stream>>>(x, w, out);
}